// Round 1
// baseline (89.545 us; speedup 1.0000x reference)
//
#include <hip/hip_runtime.h>
#include <hip/hip_bf16.h>
#include <cstdint>

#define B_ROWS 8192
#define DIM    1024
#define NC     8
#define MAXT   72   // max row tiles: floor(8192/128) + 8 partials

typedef __bf16 bf16;
typedef __bf16 bf16x8 __attribute__((ext_vector_type(8)));
typedef float  f32x4  __attribute__((ext_vector_type(4)));

typedef __attribute__((address_space(3))) void* lds_vp;
typedef const __attribute__((address_space(1))) void* gbl_vp;

// ---------------- fp32 -> bf16 conversion (vectorized, 8 elems/thread) ----
__global__ void cvt_kernel(const float* __restrict__ src, bf16* __restrict__ dst, int n8) {
    int i = blockIdx.x * blockDim.x + threadIdx.x;
    if (i >= n8) return;
    const float4* s4 = (const float4*)src;
    float4 a = s4[2 * (size_t)i];
    float4 b = s4[2 * (size_t)i + 1];
    bf16x8 o;
    o[0] = (bf16)a.x; o[1] = (bf16)a.y; o[2] = (bf16)a.z; o[3] = (bf16)a.w;
    o[4] = (bf16)b.x; o[5] = (bf16)b.y; o[6] = (bf16)b.z; o[7] = (bf16)b.w;
    *(bf16x8*)(dst + 8 * (size_t)i) = o;
}

// ---------------- bias_sum[d] = sum_c b[c][d] ------------------------------
__global__ void bias_kernel(const float* __restrict__ b, float* __restrict__ bias_sum) {
    int d = blockIdx.x * blockDim.x + threadIdx.x;
    if (d < DIM) {
        float s = 0.f;
#pragma unroll
        for (int c = 0; c < NC; c++) s += b[c * DIM + d];
        bias_sum[d] = s;
    }
}

// ---------------- bucket rows by condition, build tile map -----------------
// meta layout: [0]=n_tiles, [1..MAXT]=tile_cond, [1+MAXT..]=tile_rowstart,
//              [1+2*MAXT..]=tile_rowcnt
__global__ void route_kernel(const int* __restrict__ ids, int* __restrict__ row_list,
                             int* __restrict__ meta) {
    __shared__ int cnt[NC];
    __shared__ int off[NC + 1];
    int tid = threadIdx.x;
    if (tid < NC) cnt[tid] = 0;
    __syncthreads();

    int local[NC];
#pragma unroll
    for (int c = 0; c < NC; c++) local[c] = 0;
    const int per = B_ROWS / 256;  // 32
    int base = tid * per;
    for (int j = 0; j < per; j++) local[ids[base + j]]++;
    int mybase[NC];
#pragma unroll
    for (int c = 0; c < NC; c++) mybase[c] = atomicAdd(&cnt[c], local[c]);
    __syncthreads();

    if (tid == 0) {
        int acc = 0, nt = 0;
        for (int c = 0; c < NC; c++) {
            off[c] = acc;
            int n = cnt[c];
            int start = acc;
            acc += n;
            int t = 0;
            while (t * 128 < n) {
                meta[1 + nt]            = c;
                meta[1 + MAXT + nt]     = start + t * 128;
                int rem = n - t * 128;
                meta[1 + 2 * MAXT + nt] = rem < 128 ? rem : 128;
                nt++; t++;
            }
        }
        off[NC] = acc;
        meta[0] = nt;
    }
    __syncthreads();

    int pos[NC];
#pragma unroll
    for (int c = 0; c < NC; c++) pos[c] = off[c] + mybase[c];
    for (int j = 0; j < per; j++) {
        int id = ids[base + j];
        row_list[pos[id]++] = base + j;
    }
}

// ---------------- grouped GEMM: out = gather(x_bf16) @ W[c]^T + bias -------
// 128x128 tile, BK=64, 4 waves, 16x16x32 bf16 MFMA, global_load_lds staging.
__global__ __launch_bounds__(256, 2) void gemm_kernel(
    const bf16* __restrict__ xb, const bf16* __restrict__ wb,
    const float* __restrict__ bias_sum, const int* __restrict__ row_list,
    const int* __restrict__ meta, float* __restrict__ out) {
    int tileIdx = blockIdx.x;
    int n_tiles = meta[0];
    if (tileIdx >= n_tiles) return;
    int cond   = meta[1 + tileIdx];
    int rstart = meta[1 + MAXT + tileIdx];
    int rcnt   = meta[1 + 2 * MAXT + tileIdx];
    int col0   = blockIdx.y * 128;

    __shared__ bf16 lA[128 * 64];
    __shared__ bf16 lB[128 * 64];

    int tid  = threadIdx.x;
    int lane = tid & 63;
    int w    = tid >> 6;       // wave 0..3
    int wr   = w >> 1;         // wave row (0..1)
    int wc   = w & 1;          // wave col (0..1)

    // staging source pointers (per lane): 8 rows x 64 k per wave-issue
    int srow = lane >> 3;            // 0..7
    int scol = (lane & 7) * 8;       // bf16 column offset (16B granules)
    const bf16* aSrc[4];
    const bf16* bSrc[4];
#pragma unroll
    for (int i = 0; i < 4; i++) {
        int tr = w * 32 + i * 8 + srow;           // A tile row 0..127
        int rr = (tr < rcnt) ? tr : 0;            // clamp masked rows to a valid one
        int grow = row_list[rstart + rr];
        aSrc[i] = xb + (size_t)grow * DIM + scol;
        int wrow = col0 + w * 32 + i * 8 + srow;  // output-feature row of W
        bSrc[i] = wb + (size_t)cond * DIM * DIM + (size_t)wrow * DIM + scol;
    }

    f32x4 acc[4][4];
#pragma unroll
    for (int m = 0; m < 4; m++)
#pragma unroll
        for (int n = 0; n < 4; n++) acc[m][n] = (f32x4){0.f, 0.f, 0.f, 0.f};

    int fr = lane & 15;   // fragment M (A) / N (B) index
    int fq = lane >> 4;   // 0..3 -> k sub-block
    const bf16* lApt = lA + (wr * 64 + fr) * 64 + fq * 8;
    const bf16* lBpt = lB + (wc * 64 + fr) * 64 + fq * 8;

    for (int k0 = 0; k0 < DIM; k0 += 64) {
        __syncthreads();  // previous compute done before overwrite
#pragma unroll
        for (int i = 0; i < 4; i++) {
            __builtin_amdgcn_global_load_lds((gbl_vp)(aSrc[i] + k0),
                                             (lds_vp)(lA + (w * 32 + i * 8) * 64),
                                             16, 0, 0);
            __builtin_amdgcn_global_load_lds((gbl_vp)(bSrc[i] + k0),
                                             (lds_vp)(lB + (w * 32 + i * 8) * 64),
                                             16, 0, 0);
        }
        __syncthreads();  // compiler drains vmcnt before the barrier
#pragma unroll
        for (int kk = 0; kk < 2; kk++) {
            bf16x8 af[4], bfv[4];
#pragma unroll
            for (int m = 0; m < 4; m++)
                af[m] = *(const bf16x8*)(lApt + m * 16 * 64 + kk * 32);
#pragma unroll
            for (int n = 0; n < 4; n++)
                bfv[n] = *(const bf16x8*)(lBpt + n * 16 * 64 + kk * 32);
#pragma unroll
            for (int m = 0; m < 4; m++)
#pragma unroll
                for (int n = 0; n < 4; n++)
                    acc[m][n] = __builtin_amdgcn_mfma_f32_16x16x32_bf16(
                        af[m], bfv[n], acc[m][n], 0, 0, 0);
        }
    }

    // epilogue: + bias_sum, scatter rows back through row_list
    float bias[4];
#pragma unroll
    for (int n = 0; n < 4; n++) bias[n] = bias_sum[col0 + wc * 64 + n * 16 + fr];
#pragma unroll
    for (int m = 0; m < 4; m++) {
#pragma unroll
        for (int i = 0; i < 4; i++) {
            int rl = wr * 64 + m * 16 + fq * 4 + i;
            if (rl < rcnt) {
                int grow = row_list[rstart + rl];
                float* op = out + (size_t)grow * DIM + col0 + wc * 64 + fr;
#pragma unroll
                for (int n = 0; n < 4; n++) op[n * 16] = acc[m][n][i] + bias[n];
            }
        }
    }
}

// ---------------- naive fallback (only if ws too small) --------------------
__global__ void naive_kernel(const float* __restrict__ x, const int* __restrict__ ids,
                             const float* __restrict__ W, const float* __restrict__ b,
                             float* __restrict__ out) {
    int row = blockIdx.x;
    int c = ids[row];
    __shared__ float xs[DIM];
    for (int i = threadIdx.x; i < DIM; i += 256) xs[i] = x[(size_t)row * DIM + i];
    __syncthreads();
    const float* Wc = W + (size_t)c * DIM * DIM;
    for (int o = threadIdx.x; o < DIM; o += 256) {
        float s = 0.f;
        const float* wrp = Wc + (size_t)o * DIM;
        for (int i = 0; i < DIM; i++) s += xs[i] * wrp[i];
        float bs = 0.f;
#pragma unroll
        for (int cc = 0; cc < NC; cc++) bs += b[cc * DIM + o];
        out[(size_t)row * DIM + o] = s + bs;
    }
}

extern "C" void kernel_launch(void* const* d_in, const int* in_sizes, int n_in,
                              void* d_out, int out_size, void* d_ws, size_t ws_size,
                              hipStream_t stream) {
    const float* x   = (const float*)d_in[0];
    const int*   ids = (const int*)d_in[1];
    const float* W   = (const float*)d_in[2];
    const float* b   = (const float*)d_in[3];
    float*       out = (float*)d_out;

    size_t xb_off   = 0;
    size_t wb_off   = (size_t)B_ROWS * DIM * 2;               // 16 MB
    size_t bias_off = wb_off + (size_t)NC * DIM * DIM * 2;    // +16 MB
    size_t rl_off   = bias_off + (size_t)DIM * 4;
    size_t meta_off = rl_off + (size_t)B_ROWS * 4;
    size_t need     = meta_off + (size_t)(1 + 3 * MAXT) * 4;

    if (ws_size < need) {  // emergency correct-but-slow path
        naive_kernel<<<dim3(B_ROWS), dim3(256), 0, stream>>>(x, ids, W, b, out);
        return;
    }

    char* ws = (char*)d_ws;
    bf16*  xb       = (bf16*)(ws + xb_off);
    bf16*  wbf      = (bf16*)(ws + wb_off);
    float* bias_sum = (float*)(ws + bias_off);
    int*   row_list = (int*)(ws + rl_off);
    int*   meta     = (int*)(ws + meta_off);

    cvt_kernel<<<dim3((B_ROWS * DIM / 8) / 256), dim3(256), 0, stream>>>(x, xb, B_ROWS * DIM / 8);
    cvt_kernel<<<dim3((NC * DIM * DIM / 8) / 256), dim3(256), 0, stream>>>(W, wbf, NC * DIM * DIM / 8);
    bias_kernel<<<dim3(DIM / 256), dim3(256), 0, stream>>>(b, bias_sum);
    route_kernel<<<dim3(1), dim3(256), 0, stream>>>(ids, row_list, meta);
    gemm_kernel<<<dim3(MAXT, DIM / 128), dim3(256), 0, stream>>>(xb, wbf, bias_sum, row_list, meta, out);
}